// Round 4
// baseline (208.313 us; speedup 1.0000x reference)
//
#include <hip/hip_runtime.h>
#include <math.h>

#define TEMP_INV (1.0f / 0.07f)
#define WEIGHT 0.5f
#define EPS 1e-8f
#define BB 64
#define TT 512
#define DD 512
#define ROWS_PER_BLOCK 16   // 16 rows * 2 KB = 32 KB LDS tile per block

// async global->LDS, 16 B per lane per issue (m97-proven width)
#define GLOAD_LDS(gp, lp)                                              \
    __builtin_amdgcn_global_load_lds(                                  \
        (const __attribute__((address_space(1))) void*)(gp),           \
        (__attribute__((address_space(3))) void*)(lp), 16, 0, 0)

__device__ inline float wave_sum(float v) {
    for (int o = 32; o >= 1; o >>= 1) v += __shfl_xor(v, o, 64);
    return v;
}
__device__ inline int wave_max_i(int v) {
    for (int o = 32; o >= 1; o >>= 1) v = max(v, __shfl_xor(v, o, 64));
    return v;
}
__device__ inline int wave_min_i(int v) {
    for (int o = 32; o >= 1; o >>= 1) v = min(v, __shfl_xor(v, o, 64));
    return v;
}

// One block (256 threads) per batch element b:
//  - argmax(mask[b,:]) with first-occurrence semantics
//  - normalized anchors a_anchor[b,:], v_anchor[b,:]
//  - pos[b] = dot(v_anchor_n, a_anchor_n)/TEMP
//  - zero the neg accumulators (ws is poisoned each call)
__global__ __launch_bounds__(256) void prep_kernel(
    const float* __restrict__ video, const float* __restrict__ audio,
    const int* __restrict__ mask,
    float* __restrict__ a_anchor, float* __restrict__ v_anchor,
    float* __restrict__ pos, float* __restrict__ neg, int* __restrict__ idx_out)
{
    const int b = blockIdx.x;
    const int tid = threadIdx.x;
    const int wid = tid >> 6, lane = tid & 63;
    __shared__ int sh_i[4];
    __shared__ float sh_f[4][3];
    __shared__ int s_idx;
    __shared__ float s_inva, s_invv;

    // ---- argmax (first max) over mask[b, 0..T) ----
    int m0 = mask[b * TT + tid];
    int m1 = mask[b * TT + tid + 256];
    int vmax = wave_max_i(max(m0, m1));
    if (lane == 0) sh_i[wid] = vmax;
    __syncthreads();
    if (tid == 0) {
        int r = sh_i[0];
        for (int i = 1; i < 4; i++) r = max(r, sh_i[i]);
        sh_i[0] = r;
    }
    __syncthreads();
    vmax = sh_i[0];
    __syncthreads();
    int cand = (m0 == vmax) ? tid : 0x7fffffff;
    int cand1 = (m1 == vmax) ? (tid + 256) : 0x7fffffff;
    cand = min(cand, cand1);
    cand = wave_min_i(cand);
    if (lane == 0) sh_i[wid] = cand;
    __syncthreads();
    if (tid == 0) {
        int r = sh_i[0];
        for (int i = 1; i < 4; i++) r = min(r, sh_i[i]);
        s_idx = r;
    }
    __syncthreads();
    const int idx = s_idx;

    // ---- anchor rows: sumsq(audio), sumsq(video), dot(audio,video) ----
    const float* arow = audio + ((size_t)(b * TT + idx)) * DD;
    const float* vrow = video + ((size_t)(b * TT + idx)) * DD;
    float a0 = arow[tid], a1 = arow[tid + 256];
    float v0 = vrow[tid], v1 = vrow[tid + 256];
    float ssa = a0 * a0 + a1 * a1;
    float ssv = v0 * v0 + v1 * v1;
    float dav = a0 * v0 + a1 * v1;
    ssa = wave_sum(ssa);
    ssv = wave_sum(ssv);
    dav = wave_sum(dav);
    if (lane == 0) { sh_f[wid][0] = ssa; sh_f[wid][1] = ssv; sh_f[wid][2] = dav; }
    __syncthreads();
    if (tid == 0) {
        float ra = 0.f, rv = 0.f, rd = 0.f;
        for (int i = 0; i < 4; i++) { ra += sh_f[i][0]; rv += sh_f[i][1]; rd += sh_f[i][2]; }
        float inva = 1.0f / fmaxf(sqrtf(ra), EPS);
        float invv = 1.0f / fmaxf(sqrtf(rv), EPS);
        s_inva = inva; s_invv = invv;
        pos[b] = rd * inva * invv * TEMP_INV;
        neg[b] = 0.0f;
        neg[BB + b] = 0.0f;
        idx_out[b] = idx;
    }
    __syncthreads();
    const float inva = s_inva, invv = s_invv;
    a_anchor[b * DD + tid] = a0 * inva;
    a_anchor[b * DD + tid + 256] = a1 * inva;
    v_anchor[b * DD + tid] = v0 * invv;
    v_anchor[b * DD + tid + 256] = v1 * invv;
}

// grid (T/ROWS_PER_BLOCK, B, 2). Each block stages a 16-row (32 KB) tile
// into LDS via async global_load_lds (2048 outstanding 16B requests — the
// MLP lives in the DMA queue, not in VGPRs), then each wave reduces 4 rows:
// 2 x ds_read_b128 per row per lane, batched butterfly, 1 atomic per wave.
// 32 KB LDS -> 5 blocks/CU co-resident: drain of one block overlaps compute
// of the others.
__global__ __launch_bounds__(256) void sims_kernel(
    const float* __restrict__ video, const float* __restrict__ audio,
    const float* __restrict__ a_anchor, const float* __restrict__ v_anchor,
    const int* __restrict__ idx_arr, float* __restrict__ neg)
{
    const int b = blockIdx.y;
    const int dir = blockIdx.z;
    const int tid = threadIdx.x;
    const int wid = tid >> 6, lane = tid & 63;
    const int t0 = blockIdx.x * ROWS_PER_BLOCK;

    __shared__ float lds[ROWS_PER_BLOCK * DD];  // 32 KB

    const float* base = (dir == 0 ? video : audio)
                      + (size_t)b * TT * DD + (size_t)t0 * DD;

    // stage 32 KB: 8 async issues per thread, each 16 B.
    // LDS dest is wave-uniform base + lane*16; passing &lds[(i*256+tid)*4]
    // makes firstlane(addr) + lane*16 == the linear copy we want.
#pragma unroll
    for (int i = 0; i < 8; i++) {
        GLOAD_LDS(base + (i * 256 + tid) * 4, &lds[(i * 256 + tid) * 4]);
    }

    // anchor fragment: lane covers 8 contiguous elements of the anchor
    const float* anc = (dir == 0 ? a_anchor : v_anchor) + b * DD;
    float4 c0 = *(const float4*)(anc + lane * 8);
    float4 c1 = *(const float4*)(anc + lane * 8 + 4);

    __syncthreads();  // drains vmcnt(0): all DMA landed

    // wave w reduces rows 4w..4w+3
    float dot[4], nrm[4];
#pragma unroll
    for (int r = 0; r < 4; r++) {
        const float* row = &lds[(wid * 4 + r) * DD];
        float4 x0 = *(const float4*)(row + lane * 8);
        float4 x1 = *(const float4*)(row + lane * 8 + 4);
        dot[r] = x0.x * c0.x + x0.y * c0.y + x0.z * c0.z + x0.w * c0.w
               + x1.x * c1.x + x1.y * c1.y + x1.z * c1.z + x1.w * c1.w;
        nrm[r] = x0.x * x0.x + x0.y * x0.y + x0.z * x0.z + x0.w * x0.w
               + x1.x * x1.x + x1.y * x1.y + x1.z * x1.z + x1.w * x1.w;
    }

    // batched butterfly: 6 levels, 8 independent shfl-adds per level
#pragma unroll
    for (int o = 32; o >= 1; o >>= 1) {
#pragma unroll
        for (int r = 0; r < 4; r++) {
            dot[r] += __shfl_xor(dot[r], o, 64);
            nrm[r] += __shfl_xor(nrm[r], o, 64);
        }
    }

    if (lane == 0) {
        const int idx = idx_arr[b];
        float local = 0.0f;
#pragma unroll
        for (int r = 0; r < 4; r++) {
            const int t = t0 + wid * 4 + r;
            float sim = dot[r] / fmaxf(sqrtf(nrm[r]), EPS) * TEMP_INV;
            local += (t == idx) ? 0.0f : expf(sim);
        }
        atomicAdd(&neg[dir * BB + b], local);
    }
}

__global__ void finalize_kernel(const float* __restrict__ pos,
                                const float* __restrict__ neg,
                                float* __restrict__ out)
{
    const int b = threadIdx.x;  // 64 threads, one wave
    float term = WEIGHT * (logf(neg[b]) + logf(neg[BB + b])) - pos[b];
    term = wave_sum(term);
    if (b == 0) out[0] = term / (float)BB;
}

extern "C" void kernel_launch(void* const* d_in, const int* in_sizes, int n_in,
                              void* d_out, int out_size, void* d_ws, size_t ws_size,
                              hipStream_t stream)
{
    const float* video = (const float*)d_in[0];
    const float* audio = (const float*)d_in[1];
    const int* mask = (const int*)d_in[2];

    float* ws = (float*)d_ws;
    float* a_anchor = ws;                 // B*D
    float* v_anchor = ws + BB * DD;       // B*D
    float* pos = ws + 2 * BB * DD;        // B
    float* neg = pos + BB;                // 2*B
    int* idx = (int*)(neg + 2 * BB);      // B

    prep_kernel<<<BB, 256, 0, stream>>>(video, audio, mask, a_anchor, v_anchor, pos, neg, idx);
    dim3 grid(TT / ROWS_PER_BLOCK, BB, 2);
    sims_kernel<<<grid, 256, 0, stream>>>(video, audio, a_anchor, v_anchor, idx, neg);
    finalize_kernel<<<1, 64, 0, stream>>>(pos, neg, (float*)d_out);
}

// Round 6
// 206.530 us; speedup vs baseline: 1.0086x; 1.0086x over previous
//
#include <hip/hip_runtime.h>
#include <math.h>

#define TEMP_INV (1.0f / 0.07f)
#define WEIGHT 0.5f
#define EPS 1e-8f
#define BB 64
#define TT 512
#define DD 512
#define RR 4   // rows per wave in sims_kernel

typedef float f32x4 __attribute__((ext_vector_type(4)));

__device__ inline float wave_sum(float v) {
    for (int o = 32; o >= 1; o >>= 1) v += __shfl_xor(v, o, 64);
    return v;
}
__device__ inline int wave_max_i(int v) {
    for (int o = 32; o >= 1; o >>= 1) v = max(v, __shfl_xor(v, o, 64));
    return v;
}
__device__ inline int wave_min_i(int v) {
    for (int o = 32; o >= 1; o >>= 1) v = min(v, __shfl_xor(v, o, 64));
    return v;
}

// One block (256 threads) per batch element b:
//  - argmax(mask[b,:]) with first-occurrence semantics
//  - normalized anchors a_anchor[b,:], v_anchor[b,:]
//  - pos[b] = dot(v_anchor_n, a_anchor_n)/TEMP
//  - zero the neg accumulators (ws is poisoned each call)
__global__ __launch_bounds__(256) void prep_kernel(
    const float* __restrict__ video, const float* __restrict__ audio,
    const int* __restrict__ mask,
    float* __restrict__ a_anchor, float* __restrict__ v_anchor,
    float* __restrict__ pos, float* __restrict__ neg, int* __restrict__ idx_out)
{
    const int b = blockIdx.x;
    const int tid = threadIdx.x;
    const int wid = tid >> 6, lane = tid & 63;
    __shared__ int sh_i[4];
    __shared__ float sh_f[4][3];
    __shared__ int s_idx;
    __shared__ float s_inva, s_invv;

    // ---- argmax (first max) over mask[b, 0..T) ----
    int m0 = mask[b * TT + tid];
    int m1 = mask[b * TT + tid + 256];
    int vmax = wave_max_i(max(m0, m1));
    if (lane == 0) sh_i[wid] = vmax;
    __syncthreads();
    if (tid == 0) {
        int r = sh_i[0];
        for (int i = 1; i < 4; i++) r = max(r, sh_i[i]);
        sh_i[0] = r;
    }
    __syncthreads();
    vmax = sh_i[0];
    __syncthreads();
    int cand = (m0 == vmax) ? tid : 0x7fffffff;
    int cand1 = (m1 == vmax) ? (tid + 256) : 0x7fffffff;
    cand = min(cand, cand1);
    cand = wave_min_i(cand);
    if (lane == 0) sh_i[wid] = cand;
    __syncthreads();
    if (tid == 0) {
        int r = sh_i[0];
        for (int i = 1; i < 4; i++) r = min(r, sh_i[i]);
        s_idx = r;
    }
    __syncthreads();
    const int idx = s_idx;

    // ---- anchor rows: sumsq(audio), sumsq(video), dot(audio,video) ----
    const float* arow = audio + ((size_t)(b * TT + idx)) * DD;
    const float* vrow = video + ((size_t)(b * TT + idx)) * DD;
    float a0 = arow[tid], a1 = arow[tid + 256];
    float v0 = vrow[tid], v1 = vrow[tid + 256];
    float ssa = a0 * a0 + a1 * a1;
    float ssv = v0 * v0 + v1 * v1;
    float dav = a0 * v0 + a1 * v1;
    ssa = wave_sum(ssa);
    ssv = wave_sum(ssv);
    dav = wave_sum(dav);
    if (lane == 0) { sh_f[wid][0] = ssa; sh_f[wid][1] = ssv; sh_f[wid][2] = dav; }
    __syncthreads();
    if (tid == 0) {
        float ra = 0.f, rv = 0.f, rd = 0.f;
        for (int i = 0; i < 4; i++) { ra += sh_f[i][0]; rv += sh_f[i][1]; rd += sh_f[i][2]; }
        float inva = 1.0f / fmaxf(sqrtf(ra), EPS);
        float invv = 1.0f / fmaxf(sqrtf(rv), EPS);
        s_inva = inva; s_invv = invv;
        pos[b] = rd * inva * invv * TEMP_INV;
        neg[b] = 0.0f;
        neg[BB + b] = 0.0f;
        idx_out[b] = idx;
    }
    __syncthreads();
    const float inva = s_inva, invv = s_invv;
    a_anchor[b * DD + tid] = a0 * inva;
    a_anchor[b * DD + tid + 256] = a1 * inva;
    v_anchor[b * DD + tid] = v0 * invv;
    v_anchor[b * DD + tid + 256] = v1 * invv;
}

// grid (T/(4*RR), B, 2); one 64-lane wave per RR=4 consecutive rows.
// All 10 global_load_dwordx4 (8 row-halves + 2 anchor-halves) plus the
// s_waitcnt live in ONE asm block with early-clobber outputs: the compiler
// cannot serialize, reorder, or register-recycle mid-flight (R5's NaN was
// exactly that hazard — separate asm statements let it reuse dest VGPRs of
// in-flight loads for later addresses). Guaranteed 10-deep MLP per wave.
__global__ __launch_bounds__(256) void sims_kernel(
    const float* __restrict__ video, const float* __restrict__ audio,
    const float* __restrict__ a_anchor, const float* __restrict__ v_anchor,
    const int* __restrict__ idx_arr, float* __restrict__ neg)
{
    const int b = blockIdx.y;
    const int dir = blockIdx.z;
    const int wid = threadIdx.x >> 6, lane = threadIdx.x & 63;
    const int t0 = blockIdx.x * (4 * RR) + wid * RR;

    const float* base = (dir == 0 ? video : audio) + (size_t)b * TT * DD;
    const float* anc = (dir == 0 ? a_anchor : v_anchor) + b * DD;

    const float* p01 = base + (size_t)t0 * DD + lane * 4;  // rows t0, t0+1
    const float* p23 = p01 + 2 * DD;                        // rows t0+2, t0+3
    const float* pa  = anc + lane * 4;

    f32x4 r00, r01, r10, r11, r20, r21, r30, r31, c0, c1;
    asm volatile(
        "global_load_dwordx4 %0, %10, off\n\t"
        "global_load_dwordx4 %1, %10, off offset:1024\n\t"
        "global_load_dwordx4 %2, %10, off offset:2048\n\t"
        "global_load_dwordx4 %3, %10, off offset:3072\n\t"
        "global_load_dwordx4 %4, %11, off\n\t"
        "global_load_dwordx4 %5, %11, off offset:1024\n\t"
        "global_load_dwordx4 %6, %11, off offset:2048\n\t"
        "global_load_dwordx4 %7, %11, off offset:3072\n\t"
        "global_load_dwordx4 %8, %12, off\n\t"
        "global_load_dwordx4 %9, %12, off offset:1024\n\t"
        "s_waitcnt vmcnt(0)"
        : "=&v"(r00), "=&v"(r01), "=&v"(r10), "=&v"(r11),
          "=&v"(r20), "=&v"(r21), "=&v"(r30), "=&v"(r31),
          "=&v"(c0), "=&v"(c1)
        : "v"(p01), "v"(p23), "v"(pa)
        : "memory");

    f32x4 r0[RR] = {r00, r10, r20, r30};
    f32x4 r1[RR] = {r01, r11, r21, r31};

    float dot[RR], nrm[RR];
#pragma unroll
    for (int r = 0; r < RR; r++) {
        dot[r] = r0[r].x * c0.x + r0[r].y * c0.y + r0[r].z * c0.z + r0[r].w * c0.w
               + r1[r].x * c1.x + r1[r].y * c1.y + r1[r].z * c1.z + r1[r].w * c1.w;
        nrm[r] = r0[r].x * r0[r].x + r0[r].y * r0[r].y + r0[r].z * r0[r].z + r0[r].w * r0[r].w
               + r1[r].x * r1[r].x + r1[r].y * r1[r].y + r1[r].z * r1[r].z + r1[r].w * r1[r].w;
    }

    // batched butterfly: 6 levels, 2*RR independent shfl-adds per level
#pragma unroll
    for (int o = 32; o >= 1; o >>= 1) {
#pragma unroll
        for (int r = 0; r < RR; r++) {
            dot[r] += __shfl_xor(dot[r], o, 64);
            nrm[r] += __shfl_xor(nrm[r], o, 64);
        }
    }

    if (lane == 0) {
        const int idx = idx_arr[b];
        float local = 0.0f;
#pragma unroll
        for (int r = 0; r < RR; r++) {
            const int t = t0 + r;
            float sim = dot[r] / fmaxf(sqrtf(nrm[r]), EPS) * TEMP_INV;
            local += (t == idx) ? 0.0f : expf(sim);
        }
        atomicAdd(&neg[dir * BB + b], local);
    }
}

__global__ void finalize_kernel(const float* __restrict__ pos,
                                const float* __restrict__ neg,
                                float* __restrict__ out)
{
    const int b = threadIdx.x;  // 64 threads, one wave
    float term = WEIGHT * (logf(neg[b]) + logf(neg[BB + b])) - pos[b];
    term = wave_sum(term);
    if (b == 0) out[0] = term / (float)BB;
}

extern "C" void kernel_launch(void* const* d_in, const int* in_sizes, int n_in,
                              void* d_out, int out_size, void* d_ws, size_t ws_size,
                              hipStream_t stream)
{
    const float* video = (const float*)d_in[0];
    const float* audio = (const float*)d_in[1];
    const int* mask = (const int*)d_in[2];

    float* ws = (float*)d_ws;
    float* a_anchor = ws;                 // B*D
    float* v_anchor = ws + BB * DD;       // B*D
    float* pos = ws + 2 * BB * DD;        // B
    float* neg = pos + BB;                // 2*B
    int* idx = (int*)(neg + 2 * BB);      // B

    prep_kernel<<<BB, 256, 0, stream>>>(video, audio, mask, a_anchor, v_anchor, pos, neg, idx);
    dim3 grid(TT / (4 * RR), BB, 2);
    sims_kernel<<<grid, 256, 0, stream>>>(video, audio, a_anchor, v_anchor, idx, neg);
    finalize_kernel<<<1, 64, 0, stream>>>(pos, neg, (float*)d_out);
}

// Round 7
// 165.219 us; speedup vs baseline: 1.2608x; 1.2500x over previous
//
#include <hip/hip_runtime.h>
#include <math.h>

#define TEMP_INV (1.0f / 0.07f)
#define WEIGHT 0.5f
#define EPS 1e-8f
#define BB 64
#define TT 512
#define DD 512
#define RR 8   // rows per wave in sims_kernel (R2-proven)

__device__ inline float wave_sum(float v) {
    for (int o = 32; o >= 1; o >>= 1) v += __shfl_xor(v, o, 64);
    return v;
}
__device__ inline int wave_max_i(int v) {
    for (int o = 32; o >= 1; o >>= 1) v = max(v, __shfl_xor(v, o, 64));
    return v;
}
__device__ inline int wave_min_i(int v) {
    for (int o = 32; o >= 1; o >>= 1) v = min(v, __shfl_xor(v, o, 64));
    return v;
}

// One block (256 threads) per batch element b:
//  - argmax(mask[b,:]) with first-occurrence semantics
//  - normalized anchors a_anchor[b,:], v_anchor[b,:]
//  - pos[b] = dot(v_anchor_n, a_anchor_n)/TEMP
//  - zero the neg accumulators (ws is poisoned each call)
__global__ __launch_bounds__(256) void prep_kernel(
    const float* __restrict__ video, const float* __restrict__ audio,
    const int* __restrict__ mask,
    float* __restrict__ a_anchor, float* __restrict__ v_anchor,
    float* __restrict__ pos, float* __restrict__ neg, int* __restrict__ idx_out)
{
    const int b = blockIdx.x;
    const int tid = threadIdx.x;
    const int wid = tid >> 6, lane = tid & 63;
    __shared__ int sh_i[4];
    __shared__ float sh_f[4][3];
    __shared__ int s_idx;
    __shared__ float s_inva, s_invv;

    // ---- argmax (first max) over mask[b, 0..T) ----
    int m0 = mask[b * TT + tid];
    int m1 = mask[b * TT + tid + 256];
    int vmax = wave_max_i(max(m0, m1));
    if (lane == 0) sh_i[wid] = vmax;
    __syncthreads();
    if (tid == 0) {
        int r = sh_i[0];
        for (int i = 1; i < 4; i++) r = max(r, sh_i[i]);
        sh_i[0] = r;
    }
    __syncthreads();
    vmax = sh_i[0];
    __syncthreads();
    int cand = (m0 == vmax) ? tid : 0x7fffffff;
    int cand1 = (m1 == vmax) ? (tid + 256) : 0x7fffffff;
    cand = min(cand, cand1);
    cand = wave_min_i(cand);
    if (lane == 0) sh_i[wid] = cand;
    __syncthreads();
    if (tid == 0) {
        int r = sh_i[0];
        for (int i = 1; i < 4; i++) r = min(r, sh_i[i]);
        s_idx = r;
    }
    __syncthreads();
    const int idx = s_idx;

    // ---- anchor rows: sumsq(audio), sumsq(video), dot(audio,video) ----
    const float* arow = audio + ((size_t)(b * TT + idx)) * DD;
    const float* vrow = video + ((size_t)(b * TT + idx)) * DD;
    float a0 = arow[tid], a1 = arow[tid + 256];
    float v0 = vrow[tid], v1 = vrow[tid + 256];
    float ssa = a0 * a0 + a1 * a1;
    float ssv = v0 * v0 + v1 * v1;
    float dav = a0 * v0 + a1 * v1;
    ssa = wave_sum(ssa);
    ssv = wave_sum(ssv);
    dav = wave_sum(dav);
    if (lane == 0) { sh_f[wid][0] = ssa; sh_f[wid][1] = ssv; sh_f[wid][2] = dav; }
    __syncthreads();
    if (tid == 0) {
        float ra = 0.f, rv = 0.f, rd = 0.f;
        for (int i = 0; i < 4; i++) { ra += sh_f[i][0]; rv += sh_f[i][1]; rd += sh_f[i][2]; }
        float inva = 1.0f / fmaxf(sqrtf(ra), EPS);
        float invv = 1.0f / fmaxf(sqrtf(rv), EPS);
        s_inva = inva; s_invv = invv;
        pos[b] = rd * inva * invv * TEMP_INV;
        neg[b] = 0.0f;
        neg[BB + b] = 0.0f;
        idx_out[b] = idx;
    }
    __syncthreads();
    const float inva = s_inva, invv = s_invv;
    a_anchor[b * DD + tid] = a0 * inva;
    a_anchor[b * DD + tid + 256] = a1 * inva;
    v_anchor[b * DD + tid] = v0 * invv;
    v_anchor[b * DD + tid + 256] = v1 * invv;
}

// grid (T/16, B, 2); 128-thread blocks = 2 waves, each wave RR=8 rows.
// EXACT R2 load/compute body (plain C loads, compiler-scheduled pipeline —
// every full-drain variant [sched_barrier / LDS-DMA / asm vmcnt(0)] landed
// at ~100 us vs this structure's 61.8 us; do NOT force drains).
// 128-thread blocks give 2x finer scheduling granularity than R2's 256
// (4096 blocks vs 2048) to shrink the load-imbalance tail (occupancy 52%).
__global__ __launch_bounds__(128) void sims_kernel(
    const float* __restrict__ video, const float* __restrict__ audio,
    const float* __restrict__ a_anchor, const float* __restrict__ v_anchor,
    const int* __restrict__ idx_arr, float* __restrict__ neg)
{
    const int b = blockIdx.y;
    const int dir = blockIdx.z;
    const int wid = threadIdx.x >> 6, lane = threadIdx.x & 63;
    const int t0 = blockIdx.x * (2 * RR) + wid * RR;

    const float* base = (dir == 0 ? video : audio) + (size_t)b * TT * DD;
    const float* anc = (dir == 0 ? a_anchor : v_anchor) + b * DD;

    // anchor first: L2-hit, completes early, unblocks the FMA chain
    float4 c0 = *(const float4*)(anc + lane * 4);
    float4 c1 = *(const float4*)(anc + 256 + lane * 4);

    float4 r0[RR], r1[RR];
#pragma unroll
    for (int r = 0; r < RR; r++) {
        const float* row = base + (size_t)(t0 + r) * DD;
        r0[r] = *(const float4*)(row + lane * 4);
        r1[r] = *(const float4*)(row + 256 + lane * 4);
    }

    float dot[RR], nrm[RR];
#pragma unroll
    for (int r = 0; r < RR; r++) {
        dot[r] = r0[r].x * c0.x + r0[r].y * c0.y + r0[r].z * c0.z + r0[r].w * c0.w
               + r1[r].x * c1.x + r1[r].y * c1.y + r1[r].z * c1.z + r1[r].w * c1.w;
        nrm[r] = r0[r].x * r0[r].x + r0[r].y * r0[r].y + r0[r].z * r0[r].z + r0[r].w * r0[r].w
               + r1[r].x * r1[r].x + r1[r].y * r1[r].y + r1[r].z * r1[r].z + r1[r].w * r1[r].w;
    }

    // batched butterfly: 6 levels, 2*RR independent shfl-adds per level
#pragma unroll
    for (int o = 32; o >= 1; o >>= 1) {
#pragma unroll
        for (int r = 0; r < RR; r++) {
            dot[r] += __shfl_xor(dot[r], o, 64);
            nrm[r] += __shfl_xor(nrm[r], o, 64);
        }
    }

    if (lane == 0) {
        const int idx = idx_arr[b];
        float local = 0.0f;
#pragma unroll
        for (int r = 0; r < RR; r++) {
            const int t = t0 + r;
            float sim = dot[r] / fmaxf(sqrtf(nrm[r]), EPS) * TEMP_INV;
            local += (t == idx) ? 0.0f : expf(sim);
        }
        atomicAdd(&neg[dir * BB + b], local);
    }
}

__global__ void finalize_kernel(const float* __restrict__ pos,
                                const float* __restrict__ neg,
                                float* __restrict__ out)
{
    const int b = threadIdx.x;  // 64 threads, one wave
    float term = WEIGHT * (logf(neg[b]) + logf(neg[BB + b])) - pos[b];
    term = wave_sum(term);
    if (b == 0) out[0] = term / (float)BB;
}

extern "C" void kernel_launch(void* const* d_in, const int* in_sizes, int n_in,
                              void* d_out, int out_size, void* d_ws, size_t ws_size,
                              hipStream_t stream)
{
    const float* video = (const float*)d_in[0];
    const float* audio = (const float*)d_in[1];
    const int* mask = (const int*)d_in[2];

    float* ws = (float*)d_ws;
    float* a_anchor = ws;                 // B*D
    float* v_anchor = ws + BB * DD;       // B*D
    float* pos = ws + 2 * BB * DD;        // B
    float* neg = pos + BB;                // 2*B
    int* idx = (int*)(neg + 2 * BB);      // B

    prep_kernel<<<BB, 256, 0, stream>>>(video, audio, mask, a_anchor, v_anchor, pos, neg, idx);
    dim3 grid(TT / (2 * RR), BB, 2);
    sims_kernel<<<grid, 128, 0, stream>>>(video, audio, a_anchor, v_anchor, idx, neg);
    finalize_kernel<<<1, 64, 0, stream>>>(pos, neg, (float*)d_out);
}